// Round 11
// baseline (43.765 us; speedup 1.0000x reference)
//
#include <hip/hip_runtime.h>

#define NQ 12
#define NL 5
#define TPB 256

// ---------- compile-time address algebra (GF(2)-linear, R3-verified) ----------
__host__ __device__ constexpr int sfx12_(int x) {
    x ^= x >> 1; x ^= x >> 2; x ^= x >> 4; x ^= x >> 8;
    return x & 0xFFF;
}
__host__ __device__ constexpr int par_(int x) {
    int y = x; y ^= y >> 8; y ^= y >> 4; y ^= y >> 2; y ^= y >> 1;
    return y & 1;
}
// amp i lives at byte (G<<4)|((i&1)<<3), G = g ^ ((g>>3)&7), g = i>>1.  Linear in i.
__host__ __device__ constexpr int amp_addr(int i) {
    const int g = i >> 1;
    const int G = g ^ ((g >> 3) & 7);
    return (G << 4) | ((i & 1) << 3);
}
// CNOT ring: new[i]=old[f(i)], f(j)=j^(j>>1)^((j&1)*0xC00); f^-1(i)=sfx12(i)^(par(i)<<11).
__host__ __device__ constexpr int scat_c(int m) {          // scatter m-part address
    const int s = sfx12_(m << 8);
    return amp_addr(s ^ ((s & 1) << 11));
}
__host__ __device__ constexpr int bpat(int m) { return amp_addr(m << 4); }   // pass-B m-part
__host__ __device__ constexpr int meas_h(int m) {          // bits 11..8 of f^-1(m<<8)
    const int d = sfx12_(m << 8) ^ (par_(m) << 11);
    return (d >> 8) & 15;
}

// ---------- gate kernels ----------
__device__ __forceinline__ float2 cmul(float2 a, float2 b) {
    return make_float2(fmaf(a.x, b.x, -a.y * b.y), fmaf(a.x, b.y, a.y * b.x));
}
__device__ __forceinline__ void gate_pair(float2 &a, float2 &c,
        const float2 u00, const float2 u01, const float2 u10, const float2 u11) {
    float2 n0, n1;
    n0.x = fmaf(u00.x, a.x, fmaf(-u00.y, a.y, fmaf(u01.x, c.x, -u01.y * c.y)));
    n0.y = fmaf(u00.x, a.y, fmaf( u00.y, a.x, fmaf(u01.x, c.y,  u01.y * c.x)));
    n1.x = fmaf(u10.x, a.x, fmaf(-u10.y, a.y, fmaf(u11.x, c.x, -u11.y * c.y)));
    n1.y = fmaf(u10.x, a.y, fmaf( u10.y, a.x, fmaf(u11.x, c.y,  u11.y * c.x)));
    a = n0; c = n1;
}
template <int K>
__device__ __forceinline__ void apply_gate(float2 (&v)[16], const float2* __restrict__ Uq) {
    const float2 u00 = Uq[0], u01 = Uq[1], u10 = Uq[2], u11 = Uq[3];
#pragma unroll
    for (int h = 0; h < 8; ++h) {
        const int m0 = ((h >> K) << (K + 1)) | (h & ((1 << K) - 1));
        gate_pair(v[m0], v[m0 | (1 << K)], u00, u01, u10, u11);
    }
}

extern "C" __global__ void __launch_bounds__(TPB)
qnet_kernel(const float* __restrict__ x, const float* __restrict__ iw,
            const float* __restrict__ th, const float* __restrict__ ow,
            float* __restrict__ out) {
    __shared__ float2 st[4096];                      // 32 KB state, swizzled
    __shared__ __align__(16) float2 U[NL][NQ][4];    // gate matrices
    __shared__ float wz[4][4];
    char* stb = (char*)st;

    const int b = blockIdx.x;
    const int tid = threadIdx.x;
    const int w = tid >> 6;

    // ---- anti-convoy stagger: desynchronize co-resident blocks' pass phases ----
    // Identical blocks self-synchronize into a chip-wide convoy (LDS bursts and
    // FMA bursts align -> pipes alternate instead of overlapping). A one-time
    // ~960-cycle-per-step sleep breaks the lock; offsets persist (no inter-block
    // sync exists). (bid + (bid>>8)) covers breadth-first & depth-first dispatch.
    {
        const int ph = (b + (b >> 8)) & 3;
        for (int i = 0; i < ph; ++i) __builtin_amdgcn_s_sleep(15);
    }

    // --- precompute all 60 gate matrices U = M(b,c) @ Rx(a) ---
    if (tid < NL * NQ) {
        const int l = tid / NQ, q = tid % NQ;
        const float xv = tanhf(x[b * NQ + q]);
        const float a = iw[l * NQ + q] * xv;
        const float bt = th[(l * NQ + q) * 2 + 0];
        const float ct = th[(l * NQ + q) * 2 + 1];
        float sa, ca; sincosf(0.5f * a, &sa, &ca);
        float sb, cb; sincosf(0.5f * bt, &sb, &cb);
        float sc, cc; sincosf(0.5f * ct, &sc, &cc);
        const float M00r = cc * cb, M00i = -sc * cb;
        const float M01r = -cc * sb, M01i = sc * sb;
        const float M10r = cc * sb, M10i = sc * sb;
        const float M11r = cc * cb, M11i = sc * cb;
        U[l][q][0] = make_float2(fmaf(M00r, ca,  sa * M01i), fmaf(M00i, ca, -sa * M01r));
        U[l][q][1] = make_float2(fmaf(ca, M01r,  sa * M00i), fmaf(ca, M01i, -sa * M00r));
        U[l][q][2] = make_float2(fmaf(M10r, ca,  sa * M11i), fmaf(M10i, ca, -sa * M11r));
        U[l][q][3] = make_float2(fmaf(ca, M11r,  sa * M10i), fmaf(ca, M11i, -sa * M10r));
    }

    // --- per-thread address bases (1 XOR w/ const per LDS access in the loop) ---
    const int baseA = amp_addr(tid << 4);                              // ^ (c<<4)
    const int baseB = amp_addr(((tid >> 4) << 8) | (tid & 15));        // ^ bpat(m)
    const int baseC = amp_addr(tid);                                   // + (m<<11)
    const int pt = __popc(tid) & 1;
    const int baseS = amp_addr(sfx12_(tid) ^ (pt << 11));              // ^ scat_c(m)

    __syncthreads();   // U visible

    // ---- fused layer 0 (|0..0> is 1-hot): v[r] = psi1[(tid<<4)|r] in closed form ----
    // psi_after_gates(i) = prod_k c_k[bit_k(i)], c_k[bit] = column-0 of gate on qubit 11-k.
    // psi1(i) = psi_after_gates(f(i));  bits of j=f((t<<4)|r):
    //   j0=r0^r1 j1=r1^r2 j2=r2^r3 j3=r3^t0 j4=t0^t1 ... j9=t5^t6 j10=t6^t7^r0 j11=t7^r0
    float2 v[16];
    {
        const int t0 = tid & 1, t1 = (tid >> 1) & 1, t2 = (tid >> 2) & 1, t3 = (tid >> 3) & 1;
        const int t4 = (tid >> 4) & 1, t5 = (tid >> 5) & 1, t6 = (tid >> 6) & 1, t7 = (tid >> 7) & 1;
        // c_k[bit] = U[0][11-k][bit?2:0]
        #define C0(k, bit) (U[0][11 - (k)][(bit) ? 2 : 0])
        float2 Pm = cmul(C0(4, t0 ^ t1), C0(5, t1 ^ t2));
        Pm = cmul(Pm, C0(6, t2 ^ t3));
        Pm = cmul(Pm, C0(7, t3 ^ t4));
        Pm = cmul(Pm, C0(8, t4 ^ t5));
        Pm = cmul(Pm, C0(9, t5 ^ t6));
        float2 P3[2];                       // index r3
        P3[0] = cmul(Pm, C0(3, t0));
        P3[1] = cmul(Pm, C0(3, 1 ^ t0));
        float2 H[2];                        // index r0
        H[0] = cmul(C0(10, t6 ^ t7), C0(11, t7));
        H[1] = cmul(C0(10, t6 ^ t7 ^ 1), C0(11, t7 ^ 1));
        float2 PH[2][2];                    // [r0][r3]
        PH[0][0] = cmul(H[0], P3[0]); PH[0][1] = cmul(H[0], P3[1]);
        PH[1][0] = cmul(H[1], P3[0]); PH[1][1] = cmul(H[1], P3[1]);
        float2 T01[2][2];                   // [j0][j1]
        T01[0][0] = cmul(C0(0, 0), C0(1, 0)); T01[0][1] = cmul(C0(0, 0), C0(1, 1));
        T01[1][0] = cmul(C0(0, 1), C0(1, 0)); T01[1][1] = cmul(C0(0, 1), C0(1, 1));
        float2 L8[8];                       // [j0 | j1<<1 | j2<<2]
#pragma unroll
        for (int jj = 0; jj < 8; ++jj)
            L8[jj] = cmul(T01[jj & 1][(jj >> 1) & 1], C0(2, (jj >> 2) & 1));
        #undef C0
#pragma unroll
        for (int r = 0; r < 16; ++r) {
            const int r0 = r & 1, r1 = (r >> 1) & 1, r2 = (r >> 2) & 1, r3 = (r >> 3) & 1;
            v[r] = cmul(L8[(r0 ^ r1) | ((r1 ^ r2) << 1) | ((r2 ^ r3) << 2)], PH[r0][r3]);
        }
    }

#pragma unroll
    for (int l = 1; l < NL; ++l) {
        // ---- pass A: amp bits 0-3 (qubits 11..8) ----
        if (l > 1) {
#pragma unroll
            for (int c = 0; c < 8; ++c) {
                const float4 f = *(const float4*)(stb + (baseA ^ (c << 4)));
                v[2 * c]     = make_float2(f.x, f.y);
                v[2 * c + 1] = make_float2(f.z, f.w);
            }
        }
        apply_gate<0>(v, U[l][11]);
        apply_gate<1>(v, U[l][10]);
        apply_gate<2>(v, U[l][9]);
        apply_gate<3>(v, U[l][8]);
#pragma unroll
        for (int c = 0; c < 8; ++c)
            *(float4*)(stb + (baseA ^ (c << 4))) =
                make_float4(v[2 * c].x, v[2 * c].y, v[2 * c + 1].x, v[2 * c + 1].y);
        __syncthreads();

        // ---- pass B: amp bits 4-7 (qubits 7..4) ----
#pragma unroll
        for (int m = 0; m < 16; ++m)
            v[m] = *(const float2*)(stb + (baseB ^ bpat(m)));
        apply_gate<0>(v, U[l][7]);
        apply_gate<1>(v, U[l][6]);
        apply_gate<2>(v, U[l][5]);
        apply_gate<3>(v, U[l][4]);
#pragma unroll
        for (int m = 0; m < 16; ++m)
            *(float2*)(stb + (baseB ^ bpat(m))) = v[m];
        __syncthreads();

        // ---- pass C: amp bits 8-11 (qubits 3..0); static-offset reads ----
#pragma unroll
        for (int m = 0; m < 16; ++m)
            v[m] = *(const float2*)(stb + baseC + (m << 11));
        apply_gate<0>(v, U[l][3]);
        apply_gate<1>(v, U[l][2]);
        apply_gate<2>(v, U[l][1]);
        apply_gate<3>(v, U[l][0]);
        __syncthreads();   // all pass-C reads consumed before scatter overwrites
        if (l != NL - 1) {
            // CNOT-ring fused scatter: amp i -> address of f^-1(i)
#pragma unroll
            for (int m = 0; m < 16; ++m)
                *(float2*)(stb + (baseS ^ scat_c(m))) = v[m];
            __syncthreads();   // scatter visible to next layer's pass A
        }
    }

    // ---- layer-4: CNOT perm + measurement fused, straight from registers ----
    float z0 = 0.f, z1 = 0.f, z2 = 0.f, z3 = 0.f;
#pragma unroll
    for (int m = 0; m < 16; ++m) {
        const float pr = fmaf(v[m].x, v[m].x, v[m].y * v[m].y);
        const int h = meas_h(m) ^ ((__popc(tid) & 1) << 3);  // bits 11..8 of f^-1((m<<8)|tid)
        z0 += (h & 8) ? -pr : pr;
        z1 += (h & 4) ? -pr : pr;
        z2 += (h & 2) ? -pr : pr;
        z3 += (h & 1) ? -pr : pr;
    }
#pragma unroll
    for (int off = 32; off > 0; off >>= 1) {
        z0 += __shfl_xor(z0, off);
        z1 += __shfl_xor(z1, off);
        z2 += __shfl_xor(z2, off);
        z3 += __shfl_xor(z3, off);
    }
    if ((tid & 63) == 0) {
        wz[w][0] = z0; wz[w][1] = z1; wz[w][2] = z2; wz[w][3] = z3;
    }
    __syncthreads();
    if (tid < 4) {
        const float z = wz[0][tid] + wz[1][tid] + wz[2][tid] + wz[3][tid];
        out[b * 4 + tid] = ow[tid] * z;
    }
}

extern "C" void kernel_launch(void* const* d_in, const int* in_sizes, int n_in,
                              void* d_out, int out_size, void* d_ws, size_t ws_size,
                              hipStream_t stream) {
    const float* x  = (const float*)d_in[0];
    const float* iw = (const float*)d_in[1];
    const float* th = (const float*)d_in[2];
    const float* ow = (const float*)d_in[3];
    float* out = (float*)d_out;
    const int batch = in_sizes[0] / NQ;
    hipLaunchKernelGGL(qnet_kernel, dim3(batch), dim3(TPB), 0, stream,
                       x, iw, th, ow, out);
}

// Round 12
// 42.625 us; speedup vs baseline: 1.0267x; 1.0267x over previous
//
#include <hip/hip_runtime.h>

#define NQ 12
#define NL 5
#define TPB 256

// ---------- compile-time address algebra (GF(2)-linear, R3-verified) ----------
__host__ __device__ constexpr int sfx12_(int x) {
    x ^= x >> 1; x ^= x >> 2; x ^= x >> 4; x ^= x >> 8;
    return x & 0xFFF;
}
__host__ __device__ constexpr int par_(int x) {
    int y = x; y ^= y >> 8; y ^= y >> 4; y ^= y >> 2; y ^= y >> 1;
    return y & 1;
}
// amp i lives at byte (G<<4)|((i&1)<<3), G = g ^ ((g>>3)&7), g = i>>1.  Linear in i.
__host__ __device__ constexpr int amp_addr(int i) {
    const int g = i >> 1;
    const int G = g ^ ((g >> 3) & 7);
    return (G << 4) | ((i & 1) << 3);
}
// CNOT ring: new[i]=old[f(i)], f(j)=j^(j>>1)^((j&1)*0xC00); f^-1(i)=sfx12(i)^(par(i)<<11).
__host__ __device__ constexpr int scat_c(int m) {          // scatter m-part address
    const int s = sfx12_(m << 8);
    return amp_addr(s ^ ((s & 1) << 11));
}
__host__ __device__ constexpr int bpat(int m) { return amp_addr(m << 4); }   // pass-B m-part
__host__ __device__ constexpr int meas_h(int m) {          // bits 11..8 of f^-1(m<<8)
    const int d = sfx12_(m << 8) ^ (par_(m) << 11);
    return (d >> 8) & 15;
}

// ---------- gate kernels ----------
__device__ __forceinline__ float2 cmul(float2 a, float2 b) {
    return make_float2(fmaf(a.x, b.x, -a.y * b.y), fmaf(a.x, b.y, a.y * b.x));
}
__device__ __forceinline__ void gate_pair(float2 &a, float2 &c,
        const float2 u00, const float2 u01, const float2 u10, const float2 u11) {
    float2 n0, n1;
    n0.x = fmaf(u00.x, a.x, fmaf(-u00.y, a.y, fmaf(u01.x, c.x, -u01.y * c.y)));
    n0.y = fmaf(u00.x, a.y, fmaf( u00.y, a.x, fmaf(u01.x, c.y,  u01.y * c.x)));
    n1.x = fmaf(u10.x, a.x, fmaf(-u10.y, a.y, fmaf(u11.x, c.x, -u11.y * c.y)));
    n1.y = fmaf(u10.x, a.y, fmaf( u10.y, a.x, fmaf(u11.x, c.y,  u11.y * c.x)));
    a = n0; c = n1;
}
// gate on register-index bit K, restricted to pair-index range [H0,H1).
// For K<3: h in [0,4) touches only amps 0-7, h in [4,8) only amps 8-15.
template <int K, int H0, int H1>
__device__ __forceinline__ void apply_gate_h(float2 (&v)[16], const float2* __restrict__ Uq) {
    const float2 u00 = Uq[0], u01 = Uq[1], u10 = Uq[2], u11 = Uq[3];
#pragma unroll
    for (int h = H0; h < H1; ++h) {
        const int m0 = ((h >> K) << (K + 1)) | (h & ((1 << K) - 1));
        gate_pair(v[m0], v[m0 | (1 << K)], u00, u01, u10, u11);
    }
}

extern "C" __global__ void __launch_bounds__(TPB)
qnet_kernel(const float* __restrict__ x, const float* __restrict__ iw,
            const float* __restrict__ th, const float* __restrict__ ow,
            float* __restrict__ out) {
    __shared__ float2 st[4096];                      // 32 KB state, swizzled
    __shared__ __align__(16) float2 U[NL][NQ][4];    // gate matrices
    __shared__ float wz[4][4];
    char* stb = (char*)st;

    const int b = blockIdx.x;
    const int tid = threadIdx.x;
    const int w = tid >> 6;

    // --- precompute all 60 gate matrices U = M(b,c) @ Rx(a) ---
    if (tid < NL * NQ) {
        const int l = tid / NQ, q = tid % NQ;
        const float xv = tanhf(x[b * NQ + q]);
        const float a = iw[l * NQ + q] * xv;
        const float bt = th[(l * NQ + q) * 2 + 0];
        const float ct = th[(l * NQ + q) * 2 + 1];
        float sa, ca; sincosf(0.5f * a, &sa, &ca);
        float sb, cb; sincosf(0.5f * bt, &sb, &cb);
        float sc, cc; sincosf(0.5f * ct, &sc, &cc);
        const float M00r = cc * cb, M00i = -sc * cb;
        const float M01r = -cc * sb, M01i = sc * sb;
        const float M10r = cc * sb, M10i = sc * sb;
        const float M11r = cc * cb, M11i = sc * cb;
        U[l][q][0] = make_float2(fmaf(M00r, ca,  sa * M01i), fmaf(M00i, ca, -sa * M01r));
        U[l][q][1] = make_float2(fmaf(ca, M01r,  sa * M00i), fmaf(ca, M01i, -sa * M00r));
        U[l][q][2] = make_float2(fmaf(M10r, ca,  sa * M11i), fmaf(M10i, ca, -sa * M11r));
        U[l][q][3] = make_float2(fmaf(ca, M11r,  sa * M10i), fmaf(ca, M11i, -sa * M10r));
    }

    // --- per-thread address bases (1 XOR w/ const per LDS access in the loop) ---
    const int baseA = amp_addr(tid << 4);                              // ^ (c<<4)
    const int baseB = amp_addr(((tid >> 4) << 8) | (tid & 15));        // ^ bpat(m)
    const int baseC = amp_addr(tid);                                   // + (m<<11)
    const int pt = __popc(tid) & 1;
    const int baseS = amp_addr(sfx12_(tid) ^ (pt << 11));              // ^ scat_c(m)

    __syncthreads();   // U visible

    // ---- fused layer 0 (|0..0> is 1-hot): v[r] = psi1[(tid<<4)|r] in closed form ----
    float2 v[16];
    {
        const int t0 = tid & 1, t1 = (tid >> 1) & 1, t2 = (tid >> 2) & 1, t3 = (tid >> 3) & 1;
        const int t4 = (tid >> 4) & 1, t5 = (tid >> 5) & 1, t6 = (tid >> 6) & 1, t7 = (tid >> 7) & 1;
        #define C0(k, bit) (U[0][11 - (k)][(bit) ? 2 : 0])
        float2 Pm = cmul(C0(4, t0 ^ t1), C0(5, t1 ^ t2));
        Pm = cmul(Pm, C0(6, t2 ^ t3));
        Pm = cmul(Pm, C0(7, t3 ^ t4));
        Pm = cmul(Pm, C0(8, t4 ^ t5));
        Pm = cmul(Pm, C0(9, t5 ^ t6));
        float2 P3[2];
        P3[0] = cmul(Pm, C0(3, t0));
        P3[1] = cmul(Pm, C0(3, 1 ^ t0));
        float2 H[2];
        H[0] = cmul(C0(10, t6 ^ t7), C0(11, t7));
        H[1] = cmul(C0(10, t6 ^ t7 ^ 1), C0(11, t7 ^ 1));
        float2 PH[2][2];
        PH[0][0] = cmul(H[0], P3[0]); PH[0][1] = cmul(H[0], P3[1]);
        PH[1][0] = cmul(H[1], P3[0]); PH[1][1] = cmul(H[1], P3[1]);
        float2 T01[2][2];
        T01[0][0] = cmul(C0(0, 0), C0(1, 0)); T01[0][1] = cmul(C0(0, 0), C0(1, 1));
        T01[1][0] = cmul(C0(0, 1), C0(1, 0)); T01[1][1] = cmul(C0(0, 1), C0(1, 1));
        float2 L8[8];
#pragma unroll
        for (int jj = 0; jj < 8; ++jj)
            L8[jj] = cmul(T01[jj & 1][(jj >> 1) & 1], C0(2, (jj >> 2) & 1));
        #undef C0
#pragma unroll
        for (int r = 0; r < 16; ++r) {
            const int r0 = r & 1, r1 = (r >> 1) & 1, r2 = (r >> 2) & 1, r3 = (r >> 3) & 1;
            v[r] = cmul(L8[(r0 ^ r1) | ((r1 ^ r2) << 1) | ((r2 ^ r3) << 2)], PH[r0][r3]);
        }
    }

#pragma unroll
    for (int l = 1; l < NL; ++l) {
        // ---- pass A: amp bits 0-3 (qubits 11..8) ----
        if (l > 1) {
            // issue all reads; lower-half gates wait only on reads 0-3
            const float4 fA0 = *(const float4*)(stb + (baseA ^ 0x00));
            const float4 fA1 = *(const float4*)(stb + (baseA ^ 0x10));
            const float4 fA2 = *(const float4*)(stb + (baseA ^ 0x20));
            const float4 fA3 = *(const float4*)(stb + (baseA ^ 0x30));
            const float4 fA4 = *(const float4*)(stb + (baseA ^ 0x40));
            const float4 fA5 = *(const float4*)(stb + (baseA ^ 0x50));
            const float4 fA6 = *(const float4*)(stb + (baseA ^ 0x60));
            const float4 fA7 = *(const float4*)(stb + (baseA ^ 0x70));
            v[0] = make_float2(fA0.x, fA0.y); v[1] = make_float2(fA0.z, fA0.w);
            v[2] = make_float2(fA1.x, fA1.y); v[3] = make_float2(fA1.z, fA1.w);
            v[4] = make_float2(fA2.x, fA2.y); v[5] = make_float2(fA2.z, fA2.w);
            v[6] = make_float2(fA3.x, fA3.y); v[7] = make_float2(fA3.z, fA3.w);
            apply_gate_h<0, 0, 4>(v, U[l][11]);
            apply_gate_h<1, 0, 4>(v, U[l][10]);
            apply_gate_h<2, 0, 4>(v, U[l][9]);
            v[8]  = make_float2(fA4.x, fA4.y); v[9]  = make_float2(fA4.z, fA4.w);
            v[10] = make_float2(fA5.x, fA5.y); v[11] = make_float2(fA5.z, fA5.w);
            v[12] = make_float2(fA6.x, fA6.y); v[13] = make_float2(fA6.z, fA6.w);
            v[14] = make_float2(fA7.x, fA7.y); v[15] = make_float2(fA7.z, fA7.w);
            apply_gate_h<0, 4, 8>(v, U[l][11]);
            apply_gate_h<1, 4, 8>(v, U[l][10]);
            apply_gate_h<2, 4, 8>(v, U[l][9]);
        } else {
            apply_gate_h<0, 0, 8>(v, U[l][11]);
            apply_gate_h<1, 0, 8>(v, U[l][10]);
            apply_gate_h<2, 0, 8>(v, U[l][9]);
        }
        // gate on bit 3 (qubit 8) interleaved with b128 writes
        {
            const float2 u00 = U[l][8][0], u01 = U[l][8][1], u10 = U[l][8][2], u11 = U[l][8][3];
#pragma unroll
            for (int c2 = 0; c2 < 4; ++c2) {
                gate_pair(v[2 * c2],     v[2 * c2 + 8], u00, u01, u10, u11);
                gate_pair(v[2 * c2 + 1], v[2 * c2 + 9], u00, u01, u10, u11);
                *(float4*)(stb + (baseA ^ (c2 << 4))) =
                    make_float4(v[2 * c2].x, v[2 * c2].y, v[2 * c2 + 1].x, v[2 * c2 + 1].y);
                *(float4*)(stb + (baseA ^ ((c2 + 4) << 4))) =
                    make_float4(v[2 * c2 + 8].x, v[2 * c2 + 8].y, v[2 * c2 + 9].x, v[2 * c2 + 9].y);
            }
        }
        __syncthreads();

        // ---- pass B: amp bits 4-7 (qubits 7..4) ----
#pragma unroll
        for (int m = 0; m < 16; ++m)
            v[m] = *(const float2*)(stb + (baseB ^ bpat(m)));
        apply_gate_h<0, 0, 4>(v, U[l][7]);      // lower half: waits only reads 0-7
        apply_gate_h<1, 0, 4>(v, U[l][6]);
        apply_gate_h<2, 0, 4>(v, U[l][5]);
        apply_gate_h<0, 4, 8>(v, U[l][7]);
        apply_gate_h<1, 4, 8>(v, U[l][6]);
        apply_gate_h<2, 4, 8>(v, U[l][5]);
        {
            const float2 u00 = U[l][4][0], u01 = U[l][4][1], u10 = U[l][4][2], u11 = U[l][4][3];
#pragma unroll
            for (int m2 = 0; m2 < 8; ++m2) {
                gate_pair(v[m2], v[m2 + 8], u00, u01, u10, u11);
                *(float2*)(stb + (baseB ^ bpat(m2)))     = v[m2];
                *(float2*)(stb + (baseB ^ bpat(m2 + 8))) = v[m2 + 8];
            }
        }
        __syncthreads();

        // ---- pass C: amp bits 8-11 (qubits 3..0); static-offset reads ----
#pragma unroll
        for (int m = 0; m < 16; ++m)
            v[m] = *(const float2*)(stb + baseC + (m << 11));
        apply_gate_h<0, 0, 4>(v, U[l][3]);
        apply_gate_h<1, 0, 4>(v, U[l][2]);
        apply_gate_h<2, 0, 4>(v, U[l][1]);
        apply_gate_h<0, 4, 8>(v, U[l][3]);
        apply_gate_h<1, 4, 8>(v, U[l][2]);
        apply_gate_h<2, 4, 8>(v, U[l][1]);
        apply_gate_h<3, 0, 8>(v, U[l][0]);

        if (l != NL - 1) {
            __syncthreads();   // all pass-C reads consumed before scatter overwrites
            // CNOT-ring fused scatter: amp i -> address of f^-1(i)
#pragma unroll
            for (int m = 0; m < 16; ++m)
                *(float2*)(stb + (baseS ^ scat_c(m))) = v[m];
            __syncthreads();   // scatter visible to next layer's pass A
        }
    }

    // ---- layer-4: CNOT perm + measurement fused, straight from registers ----
    float z0 = 0.f, z1 = 0.f, z2 = 0.f, z3 = 0.f;
#pragma unroll
    for (int m = 0; m < 16; ++m) {
        const float pr = fmaf(v[m].x, v[m].x, v[m].y * v[m].y);
        const int h = meas_h(m) ^ (pt << 3);   // bits 11..8 of f^-1((m<<8)|tid)
        z0 += (h & 8) ? -pr : pr;
        z1 += (h & 4) ? -pr : pr;
        z2 += (h & 2) ? -pr : pr;
        z3 += (h & 1) ? -pr : pr;
    }
#pragma unroll
    for (int off = 32; off > 0; off >>= 1) {
        z0 += __shfl_xor(z0, off);
        z1 += __shfl_xor(z1, off);
        z2 += __shfl_xor(z2, off);
        z3 += __shfl_xor(z3, off);
    }
    if ((tid & 63) == 0) {
        wz[w][0] = z0; wz[w][1] = z1; wz[w][2] = z2; wz[w][3] = z3;
    }
    __syncthreads();
    if (tid < 4) {
        const float z = wz[0][tid] + wz[1][tid] + wz[2][tid] + wz[3][tid];
        out[b * 4 + tid] = ow[tid] * z;
    }
}

extern "C" void kernel_launch(void* const* d_in, const int* in_sizes, int n_in,
                              void* d_out, int out_size, void* d_ws, size_t ws_size,
                              hipStream_t stream) {
    const float* x  = (const float*)d_in[0];
    const float* iw = (const float*)d_in[1];
    const float* th = (const float*)d_in[2];
    const float* ow = (const float*)d_in[3];
    float* out = (float*)d_out;
    const int batch = in_sizes[0] / NQ;
    hipLaunchKernelGGL(qnet_kernel, dim3(batch), dim3(TPB), 0, stream,
                       x, iw, th, ow, out);
}